// Round 1
// baseline (403.521 us; speedup 1.0000x reference)
//
#include <hip/hip_runtime.h>
#include <hip/hip_bf16.h>

// Problem constants: B=4, T=1024, D=1024, E=8, H=2048. Tokens N = B*T = 4096.
#define NTOK 4096
#define DDIM 1024
#define HDIM 2048
#define NEXP 8

typedef __attribute__((ext_vector_type(4))) float f32x4;
typedef __attribute__((ext_vector_type(8))) short bf16x8;
typedef __attribute__((ext_vector_type(8))) unsigned short us8;

__device__ __forceinline__ unsigned short f2bf(float f) {
    unsigned u = __float_as_uint(f);
    unsigned r = (u + 0x7fffu + ((u >> 16) & 1u)) >> 16;   // RNE
    return (unsigned short)r;
}

// ---------------- Kernel 1: gate logits (fp64 accum) + argmax ----------------
__global__ void gate_kernel(const float* __restrict__ x, const float* __restrict__ gw,
                            int* __restrict__ sel) {
    int t = blockIdx.x;
    int tid = threadIdx.x, lane = tid & 63, w = tid >> 6;
    __shared__ double red[NEXP];
    const float* xr = x + (size_t)t * DDIM;
    #pragma unroll
    for (int s = 0; s < 2; ++s) {
        int e = w * 2 + s;
        const float* g = gw + (size_t)e * DDIM;
        double acc = 0.0;
        #pragma unroll
        for (int j = 0; j < DDIM / 64; ++j) {
            int d = lane + j * 64;
            acc += (double)xr[d] * (double)g[d];
        }
        #pragma unroll
        for (int off = 32; off; off >>= 1) acc += __shfl_down(acc, off);
        if (lane == 0) red[e] = acc;
    }
    __syncthreads();
    if (tid == 0) {
        int best = 0; double bv = red[0];
        #pragma unroll
        for (int e = 1; e < NEXP; ++e) if (red[e] > bv) { bv = red[e]; best = e; }
        sel[t] = best;
    }
}

// ---------------- Kernel 2: bucket tokens by expert ----------------
__global__ void scatter_kernel(const int* __restrict__ sel, int* __restrict__ cnt,
                               int* __restrict__ perm) {
    int t = blockIdx.x * blockDim.x + threadIdx.x;
    if (t < NTOK) {
        int e = sel[t];
        int p = atomicAdd(&cnt[e], 1);
        perm[e * NTOK + p] = t;
    }
}

// ---------------- Stage A: h = silu(X G) * (X U), bf16 out ----------------
// BM=64 tokens, BN=64 h-cols (per bank), BK=64. 256 threads (4 waves, 2x2).
__global__ __launch_bounds__(256) void stage_a(
        const float* __restrict__ x, const float* __restrict__ gb,
        const float* __restrict__ ub, const int* __restrict__ cnt,
        const int* __restrict__ perm, unsigned short* __restrict__ hws) {
    const int e = blockIdx.z;
    const int n0 = blockIdx.x * 64;
    const int m0 = blockIdx.y * 64;
    const int count = cnt[e];
    if (m0 >= count) return;
    const int* pl = perm + e * NTOK;

    __shared__ unsigned short Xs[64 * 64];   // [row][k] swizzled in 16B blocks
    __shared__ unsigned short Gt[64 * 64];   // [n][k]   swizzled
    __shared__ unsigned short Ut[64 * 64];

    const int tid = threadIdx.x;
    const int lane = tid & 63, w = tid >> 6;
    const int wr = w >> 1, wc = w & 1;
    const int lg = lane >> 4, li = lane & 15;

    f32x4 accG[2][2] = {{{0.f,0.f,0.f,0.f},{0.f,0.f,0.f,0.f}},{{0.f,0.f,0.f,0.f},{0.f,0.f,0.f,0.f}}};
    f32x4 accU[2][2] = {{{0.f,0.f,0.f,0.f},{0.f,0.f,0.f,0.f}},{{0.f,0.f,0.f,0.f},{0.f,0.f,0.f,0.f}}};

    const int xr = tid >> 2;                  // row this thread stages (0..63)
    int tok_x = -1;
    if (m0 + xr < count) tok_x = pl[m0 + xr];
    const int kstage = tid >> 2;              // local k row for W staging

    for (int k0 = 0; k0 < DDIM; k0 += 64) {
        __syncthreads();
        // ---- stage X (gathered rows, fp32 -> bf16, 8B vector LDS writes) ----
        {
            #pragma unroll
            for (int j = 0; j < 4; ++j) {
                int f4 = (tid & 3) + 4 * j;   // 0..15 float4 slot in row
                ushort4 v = {0, 0, 0, 0};
                if (tok_x >= 0) {
                    const float4 g = *reinterpret_cast<const float4*>(
                        x + (size_t)tok_x * DDIM + k0 + f4 * 4);
                    v.x = f2bf(g.x); v.y = f2bf(g.y); v.z = f2bf(g.z); v.w = f2bf(g.w);
                }
                int blk = f4 >> 1;
                int sb = blk ^ (xr & 7);
                *reinterpret_cast<ushort4*>(Xs + xr * 64 + sb * 8 + (f4 & 1) * 4) = v;
            }
        }
        // ---- stage G, U transposed: LDS[n][k] (scalar writes this round) ----
        {
            const float* gRow = gb + ((size_t)e * DDIM + k0 + kstage) * HDIM + n0;
            const float* uRow = ub + ((size_t)e * DDIM + k0 + kstage) * HDIM + n0;
            const int kb = kstage >> 3, ki = kstage & 7;
            #pragma unroll
            for (int j = 0; j < 4; ++j) {
                int f4 = (tid & 3) + 4 * j;
                float4 gv = *reinterpret_cast<const float4*>(gRow + f4 * 4);
                float4 uv = *reinterpret_cast<const float4*>(uRow + f4 * 4);
                #pragma unroll
                for (int c = 0; c < 4; ++c) {
                    int n = f4 * 4 + c;
                    int idx = n * 64 + ((kb ^ (n & 7)) << 3) + ki;
                    Gt[idx] = f2bf(((const float*)&gv)[c]);
                    Ut[idx] = f2bf(((const float*)&uv)[c]);
                }
            }
        }
        __syncthreads();
        // ---- compute ----
        #pragma unroll
        for (int kf = 0; kf < 2; ++kf) {
            const int kb = kf * 4 + lg;       // 16B block in 64-wide row
            bf16x8 af[2], bg[2], bu[2];
            #pragma unroll
            for (int mi = 0; mi < 2; ++mi) {
                int r = wr * 32 + mi * 16 + li;
                af[mi] = *reinterpret_cast<const bf16x8*>(Xs + r * 64 + ((kb ^ (r & 7)) << 3));
            }
            #pragma unroll
            for (int ni = 0; ni < 2; ++ni) {
                int n = wc * 32 + ni * 16 + li;
                int off = n * 64 + ((kb ^ (n & 7)) << 3);
                bg[ni] = *reinterpret_cast<const bf16x8*>(Gt + off);
                bu[ni] = *reinterpret_cast<const bf16x8*>(Ut + off);
            }
            #pragma unroll
            for (int mi = 0; mi < 2; ++mi)
                #pragma unroll
                for (int ni = 0; ni < 2; ++ni) {
                    accG[mi][ni] = __builtin_amdgcn_mfma_f32_16x16x32_bf16(af[mi], bg[ni], accG[mi][ni], 0, 0, 0);
                    accU[mi][ni] = __builtin_amdgcn_mfma_f32_16x16x32_bf16(af[mi], bu[ni], accU[mi][ni], 0, 0, 0);
                }
        }
    }
    // ---- epilogue: h = silu(a) * u -> bf16 scatter by token ----
    #pragma unroll
    for (int mi = 0; mi < 2; ++mi) {
        #pragma unroll
        for (int r = 0; r < 4; ++r) {
            int row = m0 + wr * 32 + mi * 16 + lg * 4 + r;
            if (row < count) {
                int tok = pl[row];
                #pragma unroll
                for (int ni = 0; ni < 2; ++ni) {
                    float a = accG[mi][ni][r];
                    float u = accU[mi][ni][r];
                    float h = (a / (1.0f + __expf(-a))) * u;
                    hws[(size_t)tok * HDIM + n0 + wc * 32 + ni * 16 + li] = f2bf(h);
                }
            }
        }
    }
}

// ---------------- Stage B: out = H Down, fp32 scatter ----------------
// BM=64 tokens, BN=64 d-cols, BK=64 over K=2048. 256 threads.
__global__ __launch_bounds__(256) void stage_b(
        const unsigned short* __restrict__ hws, const float* __restrict__ db,
        const int* __restrict__ cnt, const int* __restrict__ perm,
        float* __restrict__ out) {
    const int e = blockIdx.z;
    const int d0 = blockIdx.x * 64;
    const int m0 = blockIdx.y * 64;
    const int count = cnt[e];
    if (m0 >= count) return;
    const int* pl = perm + e * NTOK;

    __shared__ unsigned short Hs[64 * 64];
    __shared__ unsigned short Dt[64 * 64];   // [n=d][k=h] swizzled

    const int tid = threadIdx.x;
    const int lane = tid & 63, w = tid >> 6;
    const int wr = w >> 1, wc = w & 1;
    const int lg = lane >> 4, li = lane & 15;

    f32x4 acc[2][2] = {{{0.f,0.f,0.f,0.f},{0.f,0.f,0.f,0.f}},{{0.f,0.f,0.f,0.f},{0.f,0.f,0.f,0.f}}};

    const int xr = tid >> 2;
    int tok_x = -1;
    if (m0 + xr < count) tok_x = pl[m0 + xr];
    const int kstage = tid >> 2;

    for (int k0 = 0; k0 < HDIM; k0 += 64) {
        __syncthreads();
        // ---- stage H rows (bf16 already, 16B copies) ----
        {
            #pragma unroll
            for (int j = 0; j < 2; ++j) {
                int blk = (tid & 3) + 4 * j;  // 8-elem block 0..7
                us8 v = {0,0,0,0,0,0,0,0};
                if (tok_x >= 0)
                    v = *reinterpret_cast<const us8*>(hws + (size_t)tok_x * HDIM + k0 + blk * 8);
                int sb = blk ^ (xr & 7);
                *reinterpret_cast<us8*>(Hs + xr * 64 + sb * 8) = v;
            }
        }
        // ---- stage Down transposed ----
        {
            const float* dRow = db + ((size_t)e * HDIM + k0 + kstage) * DDIM + d0;
            const int kb = kstage >> 3, ki = kstage & 7;
            #pragma unroll
            for (int j = 0; j < 4; ++j) {
                int f4 = (tid & 3) + 4 * j;
                float4 dv = *reinterpret_cast<const float4*>(dRow + f4 * 4);
                #pragma unroll
                for (int c = 0; c < 4; ++c) {
                    int n = f4 * 4 + c;
                    int idx = n * 64 + ((kb ^ (n & 7)) << 3) + ki;
                    Dt[idx] = f2bf(((const float*)&dv)[c]);
                }
            }
        }
        __syncthreads();
        #pragma unroll
        for (int kf = 0; kf < 2; ++kf) {
            const int kb = kf * 4 + lg;
            bf16x8 af[2], bd[2];
            #pragma unroll
            for (int mi = 0; mi < 2; ++mi) {
                int r = wr * 32 + mi * 16 + li;
                af[mi] = *reinterpret_cast<const bf16x8*>(Hs + r * 64 + ((kb ^ (r & 7)) << 3));
            }
            #pragma unroll
            for (int ni = 0; ni < 2; ++ni) {
                int n = wc * 32 + ni * 16 + li;
                bd[ni] = *reinterpret_cast<const bf16x8*>(Dt + n * 64 + ((kb ^ (n & 7)) << 3));
            }
            #pragma unroll
            for (int mi = 0; mi < 2; ++mi)
                #pragma unroll
                for (int ni = 0; ni < 2; ++ni)
                    acc[mi][ni] = __builtin_amdgcn_mfma_f32_16x16x32_bf16(af[mi], bd[ni], acc[mi][ni], 0, 0, 0);
        }
    }
    // ---- epilogue: fp32 scatter to out ----
    #pragma unroll
    for (int mi = 0; mi < 2; ++mi) {
        #pragma unroll
        for (int r = 0; r < 4; ++r) {
            int row = m0 + wr * 32 + mi * 16 + lg * 4 + r;
            if (row < count) {
                int tok = pl[row];
                #pragma unroll
                for (int ni = 0; ni < 2; ++ni)
                    out[(size_t)tok * DDIM + d0 + wc * 32 + ni * 16 + li] = acc[mi][ni][r];
            }
        }
    }
}

// ---------------- launch ----------------
extern "C" void kernel_launch(void* const* d_in, const int* in_sizes, int n_in,
                              void* d_out, int out_size, void* d_ws, size_t ws_size,
                              hipStream_t stream) {
    const float* x  = (const float*)d_in[0];
    const float* gw = (const float*)d_in[1];
    const float* gb = (const float*)d_in[2];
    const float* ub = (const float*)d_in[3];
    const float* db = (const float*)d_in[4];
    float* out = (float*)d_out;

    char* ws = (char*)d_ws;
    int* cnt = (int*)(ws);                       // 8 ints (pad to 256B)
    int* sel = (int*)(ws + 256);                 // 4096 ints
    int* perm = (int*)(ws + 256 + 16384);        // 8*4096 ints
    unsigned short* hws = (unsigned short*)(ws + 256 + 16384 + 131072);  // 4096*2048 bf16

    hipMemsetAsync(cnt, 0, 256, stream);
    gate_kernel<<<NTOK, 256, 0, stream>>>(x, gw, sel);
    scatter_kernel<<<NTOK / 256, 256, 0, stream>>>(sel, cnt, perm);
    stage_a<<<dim3(HDIM / 64, NTOK / 64, NEXP), 256, 0, stream>>>(x, gb, ub, cnt, perm, hws);
    stage_b<<<dim3(DDIM / 64, NTOK / 64, NEXP), 256, 0, stream>>>(hws, db, cnt, perm, out);
}

// Round 3
// 372.038 us; speedup vs baseline: 1.0846x; 1.0846x over previous
//
#include <hip/hip_runtime.h>
#include <hip/hip_bf16.h>

// B=4, T=1024, D=1024, E=8, H=2048. Tokens N = B*T = 4096.
#define NTOK 4096
#define DDIM 1024
#define HDIM 2048
#define NEXP 8

typedef __attribute__((ext_vector_type(4))) float f32x4;
typedef __attribute__((ext_vector_type(8))) short bf16x8;
typedef __attribute__((ext_vector_type(8))) unsigned short us8;

__device__ __forceinline__ unsigned short f2bf(float f) {
    unsigned u = __float_as_uint(f);
    return (unsigned short)((u + 0x7fffu + ((u >> 16) & 1u)) >> 16);   // RNE
}

__device__ __forceinline__ void gload16(const void* g, void* l) {
    __builtin_amdgcn_global_load_lds((const __attribute__((address_space(1))) void*)g,
                                     (__attribute__((address_space(3))) void*)l, 16, 0, 0);
}

// ---------------- prep: X fp32 -> bf16 ----------------
__global__ void xcast(const float* __restrict__ x, unsigned short* __restrict__ xb) {
    int i = blockIdx.x * blockDim.x + threadIdx.x;   // float4 index
    float4 v = reinterpret_cast<const float4*>(x)[i];
    ushort4 o = { f2bf(v.x), f2bf(v.y), f2bf(v.z), f2bf(v.w) };
    reinterpret_cast<ushort4*>(xb)[i] = o;
}

// ---------------- prep: transpose-cast weight bank ----------------
// src fp32 [e][R][C] -> dst bf16 [e][orow(c)][R].
// interleave=1: orow = (c>>4)*32 + (c&15) + upoff  (gate/up 16-col interleave)
__global__ __launch_bounds__(256) void tcast(const float* __restrict__ src,
        unsigned short* __restrict__ dst, int R, int C, int interleave, int upoff,
        long long estride) {
    __shared__ unsigned short __attribute__((aligned(16))) tile[64][80];
    const int e = blockIdx.z, r0 = blockIdx.y * 64, c0 = blockIdx.x * 64;
    const float* s = src + ((size_t)e * R + r0) * C + c0;
    const int t = threadIdx.x;
    const int rd = t >> 2;
    #pragma unroll
    for (int j = 0; j < 4; ++j) {
        int c4 = (t & 3) * 4 + j;
        float4 v = *reinterpret_cast<const float4*>(s + (size_t)rd * C + c4 * 4);
        tile[c4 * 4 + 0][rd] = f2bf(v.x);
        tile[c4 * 4 + 1][rd] = f2bf(v.y);
        tile[c4 * 4 + 2][rd] = f2bf(v.z);
        tile[c4 * 4 + 3][rd] = f2bf(v.w);
    }
    __syncthreads();
    const int cr = t >> 2;
    const int c = c0 + cr;
    const int orow = interleave ? (((c >> 4) << 5) + (c & 15) + upoff) : c;
    unsigned short* drow = dst + (size_t)e * estride + (size_t)orow * R + r0;
    #pragma unroll
    for (int j = 0; j < 2; ++j) {
        int ch = (t & 3) + j * 4;
        *reinterpret_cast<us8*>(drow + ch * 8) = *reinterpret_cast<const us8*>(&tile[cr][ch * 8]);
    }
}

// ---------------- gate: fp64-accum logits + argmax ----------------
__global__ void gate_kernel(const float* __restrict__ x, const float* __restrict__ gw,
                            int* __restrict__ sel) {
    int t = blockIdx.x;
    int tid = threadIdx.x, lane = tid & 63, w = tid >> 6;
    __shared__ double red[NEXP];
    const float* xr = x + (size_t)t * DDIM;
    #pragma unroll
    for (int s = 0; s < 2; ++s) {
        int e = w * 2 + s;
        const float* g = gw + (size_t)e * DDIM;
        double acc = 0.0;
        #pragma unroll
        for (int j = 0; j < DDIM / 64; ++j) {
            int d = lane + j * 64;
            acc += (double)xr[d] * (double)g[d];
        }
        #pragma unroll
        for (int off = 32; off; off >>= 1) acc += __shfl_down(acc, off);
        if (lane == 0) red[e] = acc;
    }
    __syncthreads();
    if (tid == 0) {
        int best = 0; double bv = red[0];
        #pragma unroll
        for (int e = 1; e < NEXP; ++e) if (red[e] > bv) { bv = red[e]; best = e; }
        sel[t] = best;
    }
}

__global__ void scatter_kernel(const int* __restrict__ sel, int* __restrict__ cnt,
                               int* __restrict__ perm) {
    int t = blockIdx.x * blockDim.x + threadIdx.x;
    if (t < NTOK) {
        int e = sel[t];
        int p = atomicAdd(&cnt[e], 1);
        perm[e * NTOK + p] = t;
    }
}

// ---------------- stage A: h = silu(X G) * (X U) ----------------
// 128x128x64 tile, 4 waves (2x2), 4x4 16x16x32 frags/wave, global_load_lds w=16,
// XOR-swizzle via pre-swizzled source. N covers WA's interleaved 2H rows.
__global__ __launch_bounds__(256) void stage_a(
        const unsigned short* __restrict__ xb, const unsigned short* __restrict__ wa,
        const int* __restrict__ cnt, const int* __restrict__ perm,
        unsigned short* __restrict__ hws) {
    const int e = blockIdx.z;
    const int n0 = blockIdx.x * 128;
    const int m0 = blockIdx.y * 128;
    const int count = cnt[e];
    if (m0 >= count) return;
    const int* pl = perm + e * NTOK;

    __shared__ unsigned short __attribute__((aligned(16))) As[128 * 64];
    __shared__ unsigned short __attribute__((aligned(16))) Bs[128 * 64];

    const int tid = threadIdx.x, lane = tid & 63, w = tid >> 6;
    const int wr = w >> 1, wc = w & 1, li = lane & 15, lg = lane >> 4;
    const int sb = lane & 7, r8 = lane >> 3;
    const int srcswz = (sb ^ r8) * 8;   // inverse-swizzled source chunk (elements)

    const unsigned short* pA[4];
    const unsigned short* pB[4];
    #pragma unroll
    for (int i = 0; i < 4; ++i) {
        int row = i * 32 + w * 8 + r8;
        int tr = m0 + row; if (tr >= count) tr = count - 1;
        int tok = pl[tr];
        pA[i] = xb + (size_t)tok * DDIM + srcswz;
        pB[i] = wa + ((size_t)e * (2 * HDIM) + (size_t)(n0 + row)) * DDIM + srcswz;
    }

    f32x4 acc[4][4];
    #pragma unroll
    for (int i = 0; i < 4; ++i)
        #pragma unroll
        for (int j = 0; j < 4; ++j) acc[i][j] = (f32x4){0.f, 0.f, 0.f, 0.f};

    for (int k0 = 0; k0 < DDIM; k0 += 64) {
        #pragma unroll
        for (int i = 0; i < 4; ++i) gload16(pA[i] + k0, As + (i * 256 + w * 64) * 8);
        #pragma unroll
        for (int i = 0; i < 4; ++i) gload16(pB[i] + k0, Bs + (i * 256 + w * 64) * 8);
        asm volatile("s_waitcnt vmcnt(0)" ::: "memory");
        __syncthreads();
        #pragma unroll
        for (int kf = 0; kf < 2; ++kf) {
            bf16x8 a[4], b[4];
            const int kb = kf * 4 + lg;
            #pragma unroll
            for (int mi = 0; mi < 4; ++mi) {
                int r = wr * 64 + mi * 16 + li;
                a[mi] = *reinterpret_cast<const bf16x8*>(As + r * 64 + ((kb ^ (li & 7)) << 3));
            }
            #pragma unroll
            for (int ni = 0; ni < 4; ++ni) {
                int n = wc * 64 + ni * 16 + li;
                b[ni] = *reinterpret_cast<const bf16x8*>(Bs + n * 64 + ((kb ^ (li & 7)) << 3));
            }
            #pragma unroll
            for (int mi = 0; mi < 4; ++mi)
                #pragma unroll
                for (int ni = 0; ni < 4; ++ni)
                    acc[mi][ni] = __builtin_amdgcn_mfma_f32_16x16x32_bf16(a[mi], b[ni], acc[mi][ni], 0, 0, 0);
        }
        __syncthreads();
    }
    // epilogue: pair (G,U) fragments within lane, silu, bf16 scatter.
    // fragment acc[mi][2p+q] sits at interleaved block n0/16 + wc*4 + 2p + q
    // -> h-column = n0/2 + wc*32 + p*16 + li  (q=0 gate, q=1 up)
    const int hbase = (n0 >> 1) + wc * 32 + li;
    #pragma unroll
    for (int mi = 0; mi < 4; ++mi) {
        #pragma unroll
        for (int r = 0; r < 4; ++r) {
            int row = m0 + wr * 64 + mi * 16 + lg * 4 + r;
            if (row < count) {
                int tok = pl[row];
                #pragma unroll
                for (int p = 0; p < 2; ++p) {
                    float a = acc[mi][p * 2 + 0][r];
                    float u = acc[mi][p * 2 + 1][r];
                    float h = (a / (1.f + __expf(-a))) * u;
                    hws[(size_t)tok * HDIM + hbase + p * 16] = f2bf(h);
                }
            }
        }
    }
}

// ---------------- stage B: out = H Down ----------------
__global__ __launch_bounds__(256) void stage_b(
        const unsigned short* __restrict__ hws, const unsigned short* __restrict__ wb,
        const int* __restrict__ cnt, const int* __restrict__ perm,
        float* __restrict__ out) {
    const int e = blockIdx.z;
    const int n0 = blockIdx.x * 128;
    const int m0 = blockIdx.y * 128;
    const int count = cnt[e];
    if (m0 >= count) return;
    const int* pl = perm + e * NTOK;

    __shared__ unsigned short __attribute__((aligned(16))) As[128 * 64];
    __shared__ unsigned short __attribute__((aligned(16))) Bs[128 * 64];

    const int tid = threadIdx.x, lane = tid & 63, w = tid >> 6;
    const int wr = w >> 1, wc = w & 1, li = lane & 15, lg = lane >> 4;
    const int sb = lane & 7, r8 = lane >> 3;
    const int srcswz = (sb ^ r8) * 8;

    const unsigned short* pA[4];
    const unsigned short* pB[4];
    #pragma unroll
    for (int i = 0; i < 4; ++i) {
        int row = i * 32 + w * 8 + r8;
        int tr = m0 + row; if (tr >= count) tr = count - 1;
        int tok = pl[tr];
        pA[i] = hws + (size_t)tok * HDIM + srcswz;
        pB[i] = wb + ((size_t)e * DDIM + (size_t)(n0 + row)) * HDIM + srcswz;
    }

    f32x4 acc[4][4];
    #pragma unroll
    for (int i = 0; i < 4; ++i)
        #pragma unroll
        for (int j = 0; j < 4; ++j) acc[i][j] = (f32x4){0.f, 0.f, 0.f, 0.f};

    for (int k0 = 0; k0 < HDIM; k0 += 64) {
        #pragma unroll
        for (int i = 0; i < 4; ++i) gload16(pA[i] + k0, As + (i * 256 + w * 64) * 8);
        #pragma unroll
        for (int i = 0; i < 4; ++i) gload16(pB[i] + k0, Bs + (i * 256 + w * 64) * 8);
        asm volatile("s_waitcnt vmcnt(0)" ::: "memory");
        __syncthreads();
        #pragma unroll
        for (int kf = 0; kf < 2; ++kf) {
            bf16x8 a[4], b[4];
            const int kb = kf * 4 + lg;
            #pragma unroll
            for (int mi = 0; mi < 4; ++mi) {
                int r = wr * 64 + mi * 16 + li;
                a[mi] = *reinterpret_cast<const bf16x8*>(As + r * 64 + ((kb ^ (li & 7)) << 3));
            }
            #pragma unroll
            for (int ni = 0; ni < 4; ++ni) {
                int n = wc * 64 + ni * 16 + li;
                b[ni] = *reinterpret_cast<const bf16x8*>(Bs + n * 64 + ((kb ^ (li & 7)) << 3));
            }
            #pragma unroll
            for (int mi = 0; mi < 4; ++mi)
                #pragma unroll
                for (int ni = 0; ni < 4; ++ni)
                    acc[mi][ni] = __builtin_amdgcn_mfma_f32_16x16x32_bf16(a[mi], b[ni], acc[mi][ni], 0, 0, 0);
        }
        __syncthreads();
    }
    #pragma unroll
    for (int mi = 0; mi < 4; ++mi) {
        #pragma unroll
        for (int r = 0; r < 4; ++r) {
            int row = m0 + wr * 64 + mi * 16 + lg * 4 + r;
            if (row < count) {
                int tok = pl[row];
                #pragma unroll
                for (int ni = 0; ni < 4; ++ni)
                    out[(size_t)tok * DDIM + n0 + wc * 64 + ni * 16 + li] = acc[mi][ni][r];
            }
        }
    }
}

// ---------------- launch ----------------
extern "C" void kernel_launch(void* const* d_in, const int* in_sizes, int n_in,
                              void* d_out, int out_size, void* d_ws, size_t ws_size,
                              hipStream_t stream) {
    const float* x  = (const float*)d_in[0];
    const float* gw = (const float*)d_in[1];
    const float* gb = (const float*)d_in[2];
    const float* ub = (const float*)d_in[3];
    const float* db = (const float*)d_in[4];
    float* out = (float*)d_out;

    char* ws = (char*)d_ws;
    // wbank: WA[e][2H][D] (64 MB); reused as WB[e][D][H] (32 MB) after stage_a.
    unsigned short* wbank = (unsigned short*)(ws);
    unsigned short* hws   = (unsigned short*)(ws + 67108864);          // 16 MB
    unsigned short* xbf   = (unsigned short*)(ws + 67108864 + 16777216); // 8 MB
    char* misc = ws + 67108864 + 16777216 + 8388608;
    int* cnt  = (int*)(misc);
    int* sel  = (int*)(misc + 256);
    int* perm = (int*)(misc + 256 + 16384);

    hipMemsetAsync(cnt, 0, 256, stream);
    xcast<<<NTOK * DDIM / 4 / 256, 256, 0, stream>>>(x, xbf);
    // WA: gate_bank (R=D, C=H, interleave, upoff 0), up_bank (upoff 16)
    tcast<<<dim3(HDIM / 64, DDIM / 64, NEXP), 256, 0, stream>>>(
        gb, wbank, DDIM, HDIM, 1, 0, (long long)2 * HDIM * DDIM);
    tcast<<<dim3(HDIM / 64, DDIM / 64, NEXP), 256, 0, stream>>>(
        ub, wbank, DDIM, HDIM, 1, 16, (long long)2 * HDIM * DDIM);
    gate_kernel<<<NTOK, 256, 0, stream>>>(x, gw, sel);
    scatter_kernel<<<NTOK / 256, 256, 0, stream>>>(sel, cnt, perm);
    stage_a<<<dim3(2 * HDIM / 128, NTOK / 128, NEXP), 256, 0, stream>>>(
        xbf, wbank, cnt, perm, hws);
    // WB: down_bank (R=H, C=D) -> [e][d][h], overwrites WA (done with it)
    tcast<<<dim3(DDIM / 64, HDIM / 64, NEXP), 256, 0, stream>>>(
        db, wbank, HDIM, DDIM, 0, 0, (long long)DDIM * HDIM);
    stage_b<<<dim3(DDIM / 128, NTOK / 128, NEXP), 256, 0, stream>>>(
        hws, wbank, cnt, perm, out);
}

// Round 5
// 368.527 us; speedup vs baseline: 1.0950x; 1.0095x over previous
//
#include <hip/hip_runtime.h>
#include <hip/hip_bf16.h>

// B=4, T=1024, D=1024, E=8, H=2048. Tokens N = B*T = 4096.
#define NTOK 4096
#define DDIM 1024
#define HDIM 2048
#define NEXP 8

typedef __attribute__((ext_vector_type(4))) float f32x4;
typedef __attribute__((ext_vector_type(8))) short bf16x8;
typedef __attribute__((ext_vector_type(8))) unsigned short us8;

__device__ __forceinline__ unsigned short f2bf(float f) {
    unsigned u = __float_as_uint(f);
    return (unsigned short)((u + 0x7fffu + ((u >> 16) & 1u)) >> 16);   // RNE
}

__device__ __forceinline__ void gload16(const void* g, void* l) {
    __builtin_amdgcn_global_load_lds((const __attribute__((address_space(1))) void*)g,
                                     (__attribute__((address_space(3))) void*)l, 16, 0, 0);
}

// ------- prep: X fp32 -> bf16, fused with gate logits (fp64) + argmax -------
// one block per token; 256 threads cover the 1024-d row (4 floats/thread).
__global__ __launch_bounds__(256) void xg_kernel(
        const float* __restrict__ x, const float* __restrict__ gw,
        unsigned short* __restrict__ xb, int* __restrict__ sel) {
    const int t = blockIdx.x, tid = threadIdx.x, lane = tid & 63, w = tid >> 6;
    const float4 v = *reinterpret_cast<const float4*>(x + (size_t)t * DDIM + tid * 4);
    ushort4 o = { f2bf(v.x), f2bf(v.y), f2bf(v.z), f2bf(v.w) };
    *reinterpret_cast<ushort4*>(xb + (size_t)t * DDIM + tid * 4) = o;

    double acc[NEXP];
    #pragma unroll
    for (int e = 0; e < NEXP; ++e) {
        const float4 g = *reinterpret_cast<const float4*>(gw + (size_t)e * DDIM + tid * 4);
        acc[e] = (double)v.x * g.x + (double)v.y * g.y + (double)v.z * g.z + (double)v.w * g.w;
    }
    __shared__ double red[4][NEXP];
    #pragma unroll
    for (int e = 0; e < NEXP; ++e) {
        double a = acc[e];
        #pragma unroll
        for (int off = 32; off; off >>= 1) a += __shfl_down(a, off);
        if (lane == 0) red[w][e] = a;
    }
    __syncthreads();
    if (tid == 0) {
        int best = 0; double bv = -1e300;
        #pragma unroll
        for (int e = 0; e < NEXP; ++e) {
            double s = red[0][e] + red[1][e] + red[2][e] + red[3][e];
            if (s > bv) { bv = s; best = e; }
        }
        sel[t] = best;
    }
}

__global__ void scatter_kernel(const int* __restrict__ sel, int* __restrict__ cnt,
                               int* __restrict__ perm) {
    int t = blockIdx.x * blockDim.x + threadIdx.x;
    if (t < NTOK) {
        int e = sel[t];
        int p = atomicAdd(&cnt[e], 1);
        perm[e * NTOK + p] = t;
    }
}

// ---------------- prep: transpose-cast weight bank ----------------
// src fp32 [e][R][C] -> dst bf16 [e][orow(c)][R]; tile padded to [64][65]
// (scalar LDS ops land ~2-way bank aliasing = free on both sides).
__global__ __launch_bounds__(256) void tcast(const float* __restrict__ src,
        unsigned short* __restrict__ dst, int R, int C, int interleave, int upoff,
        long long estride) {
    __shared__ unsigned short tile[64][65];
    const int e = blockIdx.z, r0 = blockIdx.y * 64, c0 = blockIdx.x * 64;
    const float* s = src + ((size_t)e * R + r0) * C + c0;
    const int t = threadIdx.x;
    const int rd = t >> 2;
    #pragma unroll
    for (int j = 0; j < 4; ++j) {
        int c4 = (t & 3) * 4 + j;
        float4 v = *reinterpret_cast<const float4*>(s + (size_t)rd * C + c4 * 4);
        tile[c4 * 4 + 0][rd] = f2bf(v.x);
        tile[c4 * 4 + 1][rd] = f2bf(v.y);
        tile[c4 * 4 + 2][rd] = f2bf(v.z);
        tile[c4 * 4 + 3][rd] = f2bf(v.w);
    }
    __syncthreads();
    const int cr = t >> 2;
    const int c = c0 + cr;
    const int orow = interleave ? (((c >> 4) << 5) + (c & 15) + upoff) : c;
    unsigned short* drow = dst + (size_t)e * estride + (size_t)orow * R + r0;
    const int rbase = (t & 3) * 16;
    us8 v0, v1;
    #pragma unroll
    for (int s2 = 0; s2 < 8; ++s2) ((unsigned short*)&v0)[s2] = tile[cr][rbase + s2];
    #pragma unroll
    for (int s2 = 0; s2 < 8; ++s2) ((unsigned short*)&v1)[s2] = tile[cr][rbase + 8 + s2];
    *reinterpret_cast<us8*>(drow + rbase) = v0;
    *reinterpret_cast<us8*>(drow + rbase + 8) = v1;
}

// ---------------- stage A: h = silu(X G) * (X U) ----------------
// 128x128x64 tile, 4 waves (2x2), 4x4 frags, global_load_lds w=16,
// XOR-swizzle via pre-swizzled source, T3 minimal 2-phase double-buffer.
__global__ __launch_bounds__(256) void stage_a(
        const unsigned short* __restrict__ xb, const unsigned short* __restrict__ wa,
        const int* __restrict__ cnt, const int* __restrict__ perm,
        unsigned short* __restrict__ hws) {
    const int e = blockIdx.z;
    const int n0 = blockIdx.x * 128;
    const int m0 = blockIdx.y * 128;
    const int count = cnt[e];
    if (m0 >= count) return;
    const int* pl = perm + e * NTOK;

    __shared__ unsigned short __attribute__((aligned(16))) As[2][128 * 64];
    __shared__ unsigned short __attribute__((aligned(16))) Bs[2][128 * 64];

    const int tid = threadIdx.x, lane = tid & 63, w = tid >> 6;
    const int wr = w >> 1, wc = w & 1, li = lane & 15, lg = lane >> 4;
    const int sb = lane & 7, r8 = lane >> 3;
    const int srcswz = (sb ^ r8) * 8;

    const unsigned short* pA[4];
    const unsigned short* pB[4];
    #pragma unroll
    for (int i = 0; i < 4; ++i) {
        int row = i * 32 + w * 8 + r8;
        int tr = m0 + row; if (tr >= count) tr = count - 1;
        int tok = pl[tr];
        pA[i] = xb + (size_t)tok * DDIM + srcswz;
        pB[i] = wa + ((size_t)e * (2 * HDIM) + (size_t)(n0 + row)) * DDIM + srcswz;
    }

    f32x4 acc[4][4];
    #pragma unroll
    for (int i = 0; i < 4; ++i)
        #pragma unroll
        for (int j = 0; j < 4; ++j) acc[i][j] = (f32x4){0.f, 0.f, 0.f, 0.f};

    // prologue: stage k-tile 0 into buf 0
    #pragma unroll
    for (int i = 0; i < 4; ++i) gload16(pA[i], &As[0][(i * 256 + w * 64) * 8]);
    #pragma unroll
    for (int i = 0; i < 4; ++i) gload16(pB[i], &Bs[0][(i * 256 + w * 64) * 8]);
    asm volatile("s_waitcnt vmcnt(0)" ::: "memory");
    __syncthreads();

    int cur = 0;
    const int NT = DDIM / 64;
    for (int t = 0; t < NT; ++t) {
        if (t + 1 < NT) {           // issue next tile's loads BEFORE compute
            const int k0 = (t + 1) * 64;
            #pragma unroll
            for (int i = 0; i < 4; ++i) gload16(pA[i] + k0, &As[cur ^ 1][(i * 256 + w * 64) * 8]);
            #pragma unroll
            for (int i = 0; i < 4; ++i) gload16(pB[i] + k0, &Bs[cur ^ 1][(i * 256 + w * 64) * 8]);
        }
        #pragma unroll
        for (int kf = 0; kf < 2; ++kf) {
            bf16x8 a[4], b[4];
            const int kb = kf * 4 + lg;
            #pragma unroll
            for (int mi = 0; mi < 4; ++mi) {
                int r = wr * 64 + mi * 16 + li;
                a[mi] = *reinterpret_cast<const bf16x8*>(&As[cur][r * 64 + ((kb ^ (li & 7)) << 3)]);
            }
            #pragma unroll
            for (int ni = 0; ni < 4; ++ni) {
                int n = wc * 64 + ni * 16 + li;
                b[ni] = *reinterpret_cast<const bf16x8*>(&Bs[cur][n * 64 + ((kb ^ (li & 7)) << 3)]);
            }
            #pragma unroll
            for (int mi = 0; mi < 4; ++mi)
                #pragma unroll
                for (int ni = 0; ni < 4; ++ni)
                    acc[mi][ni] = __builtin_amdgcn_mfma_f32_16x16x32_bf16(a[mi], b[ni], acc[mi][ni], 0, 0, 0);
        }
        if (t + 1 < NT) {
            asm volatile("s_waitcnt vmcnt(0)" ::: "memory");
            __syncthreads();
            cur ^= 1;
        }
    }
    // epilogue: fragment acc[mi][2p+q] -> h-column n0/2 + wc*32 + p*16 + li
    const int hbase = (n0 >> 1) + wc * 32 + li;
    #pragma unroll
    for (int mi = 0; mi < 4; ++mi) {
        #pragma unroll
        for (int r = 0; r < 4; ++r) {
            int row = m0 + wr * 64 + mi * 16 + lg * 4 + r;
            if (row < count) {
                int tok = pl[row];
                #pragma unroll
                for (int p = 0; p < 2; ++p) {
                    float a = acc[mi][p * 2 + 0][r];
                    float u = acc[mi][p * 2 + 1][r];
                    float h = (a / (1.f + __expf(-a))) * u;
                    hws[(size_t)tok * HDIM + hbase + p * 16] = f2bf(h);
                }
            }
        }
    }
}

// ---------------- stage B: out = H Down ----------------
__global__ __launch_bounds__(256) void stage_b(
        const unsigned short* __restrict__ hws, const unsigned short* __restrict__ wb,
        const int* __restrict__ cnt, const int* __restrict__ perm,
        float* __restrict__ out) {
    const int e = blockIdx.z;
    const int n0 = blockIdx.x * 128;
    const int m0 = blockIdx.y * 128;
    const int count = cnt[e];
    if (m0 >= count) return;
    const int* pl = perm + e * NTOK;

    __shared__ unsigned short __attribute__((aligned(16))) As[2][128 * 64];
    __shared__ unsigned short __attribute__((aligned(16))) Bs[2][128 * 64];

    const int tid = threadIdx.x, lane = tid & 63, w = tid >> 6;
    const int wr = w >> 1, wc = w & 1, li = lane & 15, lg = lane >> 4;
    const int sb = lane & 7, r8 = lane >> 3;
    const int srcswz = (sb ^ r8) * 8;

    const unsigned short* pA[4];
    const unsigned short* pB[4];
    #pragma unroll
    for (int i = 0; i < 4; ++i) {
        int row = i * 32 + w * 8 + r8;
        int tr = m0 + row; if (tr >= count) tr = count - 1;
        int tok = pl[tr];
        pA[i] = hws + (size_t)tok * HDIM + srcswz;
        pB[i] = wb + ((size_t)e * DDIM + (size_t)(n0 + row)) * HDIM + srcswz;
    }

    f32x4 acc[4][4];
    #pragma unroll
    for (int i = 0; i < 4; ++i)
        #pragma unroll
        for (int j = 0; j < 4; ++j) acc[i][j] = (f32x4){0.f, 0.f, 0.f, 0.f};

    #pragma unroll
    for (int i = 0; i < 4; ++i) gload16(pA[i], &As[0][(i * 256 + w * 64) * 8]);
    #pragma unroll
    for (int i = 0; i < 4; ++i) gload16(pB[i], &Bs[0][(i * 256 + w * 64) * 8]);
    asm volatile("s_waitcnt vmcnt(0)" ::: "memory");
    __syncthreads();

    int cur = 0;
    const int NT = HDIM / 64;
    for (int t = 0; t < NT; ++t) {
        if (t + 1 < NT) {
            const int k0 = (t + 1) * 64;
            #pragma unroll
            for (int i = 0; i < 4; ++i) gload16(pA[i] + k0, &As[cur ^ 1][(i * 256 + w * 64) * 8]);
            #pragma unroll
            for (int i = 0; i < 4; ++i) gload16(pB[i] + k0, &Bs[cur ^ 1][(i * 256 + w * 64) * 8]);
        }
        #pragma unroll
        for (int kf = 0; kf < 2; ++kf) {
            bf16x8 a[4], b[4];
            const int kb = kf * 4 + lg;
            #pragma unroll
            for (int mi = 0; mi < 4; ++mi) {
                int r = wr * 64 + mi * 16 + li;
                a[mi] = *reinterpret_cast<const bf16x8*>(&As[cur][r * 64 + ((kb ^ (li & 7)) << 3)]);
            }
            #pragma unroll
            for (int ni = 0; ni < 4; ++ni) {
                int n = wc * 64 + ni * 16 + li;
                b[ni] = *reinterpret_cast<const bf16x8*>(&Bs[cur][n * 64 + ((kb ^ (li & 7)) << 3)]);
            }
            #pragma unroll
            for (int mi = 0; mi < 4; ++mi)
                #pragma unroll
                for (int ni = 0; ni < 4; ++ni)
                    acc[mi][ni] = __builtin_amdgcn_mfma_f32_16x16x32_bf16(a[mi], b[ni], acc[mi][ni], 0, 0, 0);
        }
        if (t + 1 < NT) {
            asm volatile("s_waitcnt vmcnt(0)" ::: "memory");
            __syncthreads();
            cur ^= 1;
        }
    }
    #pragma unroll
    for (int mi = 0; mi < 4; ++mi) {
        #pragma unroll
        for (int r = 0; r < 4; ++r) {
            int row = m0 + wr * 64 + mi * 16 + lg * 4 + r;
            if (row < count) {
                int tok = pl[row];
                #pragma unroll
                for (int ni = 0; ni < 4; ++ni)
                    out[(size_t)tok * DDIM + n0 + wc * 64 + ni * 16 + li] = acc[mi][ni][r];
            }
        }
    }
}

// ---------------- launch ----------------
extern "C" void kernel_launch(void* const* d_in, const int* in_sizes, int n_in,
                              void* d_out, int out_size, void* d_ws, size_t ws_size,
                              hipStream_t stream) {
    const float* x  = (const float*)d_in[0];
    const float* gw = (const float*)d_in[1];
    const float* gb = (const float*)d_in[2];
    const float* ub = (const float*)d_in[3];
    const float* db = (const float*)d_in[4];
    float* out = (float*)d_out;

    char* ws = (char*)d_ws;
    // wbank: WA[e][2H][D] (64 MB); reused as WB[e][D][H] (32 MB) after stage_a.
    unsigned short* wbank = (unsigned short*)(ws);
    unsigned short* hws   = (unsigned short*)(ws + 67108864);            // 16 MB
    unsigned short* xbf   = (unsigned short*)(ws + 67108864 + 16777216); // 8 MB
    char* misc = ws + 67108864 + 16777216 + 8388608;
    int* cnt  = (int*)(misc);
    int* sel  = (int*)(misc + 256);
    int* perm = (int*)(misc + 256 + 16384);

    hipMemsetAsync(cnt, 0, 256, stream);
    xg_kernel<<<NTOK, 256, 0, stream>>>(x, gw, xbf, sel);
    // WA: gate_bank (R=D, C=H, interleave, upoff 0), up_bank (upoff 16)
    tcast<<<dim3(HDIM / 64, DDIM / 64, NEXP), 256, 0, stream>>>(
        gb, wbank, DDIM, HDIM, 1, 0, (long long)2 * HDIM * DDIM);
    tcast<<<dim3(HDIM / 64, DDIM / 64, NEXP), 256, 0, stream>>>(
        ub, wbank, DDIM, HDIM, 1, 16, (long long)2 * HDIM * DDIM);
    scatter_kernel<<<NTOK / 256, 256, 0, stream>>>(sel, cnt, perm);
    stage_a<<<dim3(2 * HDIM / 128, NTOK / 128, NEXP), 256, 0, stream>>>(
        xbf, wbank, cnt, perm, hws);
    // WB: down_bank (R=H, C=D) -> [e][d][h], overwrites WA (done with it)
    tcast<<<dim3(DDIM / 64, HDIM / 64, NEXP), 256, 0, stream>>>(
        db, wbank, HDIM, DDIM, 0, 0, (long long)DDIM * HDIM);
    stage_b<<<dim3(DDIM / 128, NTOK / 128, NEXP), 256, 0, stream>>>(
        hws, wbank, cnt, perm, out);
}